// Round 16
// baseline (498.576 us; speedup 1.0000x reference)
//
#include <hip/hip_runtime.h>
#include <math.h>

#define NEG_SLOPE 0.2f
#define LOG2E 1.4426950408889634f

typedef __attribute__((ext_vector_type(8))) short short8;   // 8 bf16 = 4 VGPRs
typedef __attribute__((ext_vector_type(4))) float f32x4;    // MFMA acc

__device__ inline float b2f(unsigned short u) {
    union { unsigned int i; float f; } x; x.i = ((unsigned int)u) << 16; return x.f;
}
__device__ inline float b2f_lo(unsigned int u) {
    union { unsigned int i; float f; } x; x.i = u << 16; return x.f;
}
__device__ inline float b2f_hi(unsigned int u) {
    union { unsigned int i; float f; } x; x.i = u & 0xFFFF0000u; return x.f;
}
__device__ inline unsigned short f2b(float f) {
    union { float f; unsigned int i; } u; u.f = f;
    unsigned int r = u.i + 0x7FFF + ((u.i >> 16) & 1);   // round-to-nearest-even
    return (unsigned short)(r >> 16);
}

// ---------------- combined prep: weight transposes, u1 vectors, and ALL zero-init ----------------
__global__ void prep_kernel(const float* __restrict__ W1, const float* __restrict__ W2,
                            const float* __restrict__ W3, const float* __restrict__ as1,
                            const float* __restrict__ ad1,
                            unsigned short* __restrict__ Wt1, unsigned short* __restrict__ Wt2,
                            unsigned short* __restrict__ Wt3,
                            float* __restrict__ u1s, float* __restrict__ u1d,
                            int* __restrict__ counts, float* __restrict__ pooled,
                            float* __restrict__ cnt, int N, int G, int zc) {
    const int b = blockIdx.x;
    const int t = threadIdx.x;
    if (b < 64) {
        int i = b * 256 + t;                    // K=64, M=256
        int k = i >> 8, m = i & 255;
        Wt1[(size_t)m * 64 + k] = f2b(W1[i]);
    } else if (b < 320) {
        int i = (b - 64) * 256 + t;             // K=256, M=256
        int k = i >> 8, m = i & 255;
        Wt2[(size_t)m * 256 + k] = f2b(W2[i]);
    } else if (b < 384) {
        int i = (b - 320) * 256 + t;            // K=256, M=64
        int k = i >> 6, m = i & 63;
        Wt3[(size_t)m * 256 + k] = f2b(W3[i]);
    } else if (b == 384) {
        int k = t >> 2, h = t & 3;
        float s = 0.0f, d = 0.0f;
        for (int c = 0; c < 64; c++) {
            float w = W1[k * 256 + h * 64 + c];
            s += w * as1[h * 64 + c];
            d += w * ad1[h * 64 + c];
        }
        u1s[k * 4 + h] = s;
        u1d[k * 4 + h] = d;
    } else if (b < 385 + zc) {
        int i = (b - 385) * 256 + t;
        if (i < N) counts[i] = 0;
    } else {
        int i = (b - 385 - zc) * 256 + t;
        if (i < G * 64) pooled[i] = 0.0f;
        if (i < G) cnt[i] = 0.0f;
    }
}

// ---------------- encoder GEMM: fp32 compute, bf16 out + bias; fused conv1 scores ----------------
__global__ __launch_bounds__(256) void gemm_enc(const float* __restrict__ A,
                                                const float* __restrict__ B,
                                                const float* __restrict__ bias,
                                                unsigned short* __restrict__ C16,
                                                const float* __restrict__ u1s,
                                                const float* __restrict__ u1d,
                                                float* __restrict__ a_s,   // [N,4]
                                                float* __restrict__ a_d,
                                                int Nrows, int K, int M) {
    __shared__ float sA[16][64];
    __shared__ float sB[16][64];
    const int tx = threadIdx.x & 15;
    const int ty = threadIdx.x >> 4;
    const int row0 = blockIdx.x * 64;
    const int lr = threadIdx.x >> 2;
    const int lk = (threadIdx.x & 3) << 2;
    const int br = threadIdx.x >> 4;
    const int bc = (threadIdx.x & 15) << 2;

    const int aRow = row0 + lr;
    const bool aValid = aRow < Nrows;
    const float* Aptr = A + (size_t)aRow * K + lk;
    const float* Bptr = B + (size_t)br * M + bc;

    float acc[4][4] = {{0,0,0,0},{0,0,0,0},{0,0,0,0},{0,0,0,0}};
    float4 a = aValid ? *(const float4*)Aptr : float4{0,0,0,0};
    float4 b = *(const float4*)Bptr;

    for (int kt = 0; kt < K; kt += 16) {
        __syncthreads();
        sA[lk+0][lr] = a.x; sA[lk+1][lr] = a.y; sA[lk+2][lr] = a.z; sA[lk+3][lr] = a.w;
        *(float4*)&sB[br][bc] = b;
        __syncthreads();
        if (kt + 16 < K) {
            a = aValid ? *(const float4*)(Aptr + kt + 16) : float4{0,0,0,0};
            b = *(const float4*)(Bptr + (size_t)(kt + 16) * M);
        }
        #pragma unroll
        for (int k = 0; k < 16; k++) {
            const float4 av = *(const float4*)&sA[k][ty << 2];
            const float4 bv = *(const float4*)&sB[k][tx << 2];
            acc[0][0] += av.x*bv.x; acc[0][1] += av.x*bv.y; acc[0][2] += av.x*bv.z; acc[0][3] += av.x*bv.w;
            acc[1][0] += av.y*bv.x; acc[1][1] += av.y*bv.y; acc[1][2] += av.y*bv.z; acc[1][3] += av.y*bv.w;
            acc[2][0] += av.z*bv.x; acc[2][1] += av.z*bv.y; acc[2][2] += av.z*bv.z; acc[2][3] += av.z*bv.w;
            acc[3][0] += av.w*bv.x; acc[3][1] += av.w*bv.y; acc[3][2] += av.w*bv.z; acc[3][3] += av.w*bv.w;
        }
    }
    float4 bb = *(const float4*)&bias[tx << 2];
    #pragma unroll
    for (int i = 0; i < 4; i++) {
        acc[i][0] += bb.x; acc[i][1] += bb.y; acc[i][2] += bb.z; acc[i][3] += bb.w;
    }
    float4 us[4], ud[4];
    #pragma unroll
    for (int j = 0; j < 4; j++) {
        us[j] = *(const float4*)&u1s[((tx << 2) + j) * 4];
        ud[j] = *(const float4*)&u1d[((tx << 2) + j) * 4];
    }
    #pragma unroll
    for (int i = 0; i < 4; i++) {
        float4 ps = {0,0,0,0}, pd = {0,0,0,0};
        #pragma unroll
        for (int j = 0; j < 4; j++) {
            ps.x += acc[i][j] * us[j].x; ps.y += acc[i][j] * us[j].y;
            ps.z += acc[i][j] * us[j].z; ps.w += acc[i][j] * us[j].w;
            pd.x += acc[i][j] * ud[j].x; pd.y += acc[i][j] * ud[j].y;
            pd.z += acc[i][j] * ud[j].z; pd.w += acc[i][j] * ud[j].w;
        }
        #pragma unroll
        for (int off = 1; off < 16; off <<= 1) {
            ps.x += __shfl_xor(ps.x, off); ps.y += __shfl_xor(ps.y, off);
            ps.z += __shfl_xor(ps.z, off); ps.w += __shfl_xor(ps.w, off);
            pd.x += __shfl_xor(pd.x, off); pd.y += __shfl_xor(pd.y, off);
            pd.z += __shfl_xor(pd.z, off); pd.w += __shfl_xor(pd.w, off);
        }
        int r = row0 + (ty << 2) + i;
        if (tx == 0 && r < Nrows) {
            float4 o1 = {ps.x * LOG2E, ps.y * LOG2E, ps.z * LOG2E, ps.w * LOG2E};
            float4 o2 = {pd.x * LOG2E, pd.y * LOG2E, pd.z * LOG2E, pd.w * LOG2E};
            *(float4*)&a_s[r * 4] = o1;
            *(float4*)&a_d[r * 4] = o2;
        }
    }
    #pragma unroll
    for (int i = 0; i < 4; i++) {
        int r = row0 + (ty << 2) + i;
        if (r < Nrows) {
            ushort4 o = {f2b(acc[i][0]), f2b(acc[i][1]), f2b(acc[i][2]), f2b(acc[i][3])};
            *(ushort4*)&C16[(size_t)r * M + (tx << 2)] = o;
        }
    }
}

// ---------------- MFMA GEMM: C = A @ Wt^T; SCORES=1 also emits head-major scores and
// writes C16 HEAD-MAJOR: C16[head][row][col&63] (identical to [N,M] when M=64). ----------------
template<int CPW, int SCORES>
__global__ __launch_bounds__(256) void gemm_mfma(const unsigned short* __restrict__ A16,
                                                 const unsigned short* __restrict__ Bt16,
                                                 unsigned short* __restrict__ C16,
                                                 const float* __restrict__ att_s,
                                                 const float* __restrict__ att_d,
                                                 float* __restrict__ a_s,   // head-major [H][N]
                                                 float* __restrict__ a_d,
                                                 int Nrows, int K, int M, int H) {
    constexpr int BN = CPW * 64;
    __shared__ unsigned short sA[64][40];
    __shared__ unsigned short sB[BN][40];
    const int tid = threadIdx.x;
    const int wave = tid >> 6;
    const int lane = tid & 63;
    const int quad = lane >> 4;
    const int l16 = lane & 15;
    const int row0 = blockIdx.x * 64;
    const int col0 = blockIdx.y * BN;
    const int sr = tid >> 2;
    const int sk = (tid & 3) << 3;

    f32x4 acc[4][CPW];
    #pragma unroll
    for (int i = 0; i < 4; i++)
        #pragma unroll
        for (int j = 0; j < CPW; j++) acc[i][j] = (f32x4){0,0,0,0};

    for (int kt = 0; kt < K; kt += 32) {
        __syncthreads();
        {
            int r = row0 + sr;
            uint4 z = {0,0,0,0};
            *(uint4*)&sA[sr][sk] = (r < Nrows) ? *(const uint4*)&A16[(size_t)r * K + kt + sk] : z;
        }
        #pragma unroll
        for (int i = 0; i < CPW; i++) {
            int c = col0 + sr + i * 64;
            *(uint4*)&sB[sr + i * 64][sk] = *(const uint4*)&Bt16[(size_t)c * K + kt + sk];
        }
        __syncthreads();
        short8 bf[CPW];
        #pragma unroll
        for (int j = 0; j < CPW; j++)
            bf[j] = *(const short8*)&sB[wave * (CPW * 16) + j * 16 + l16][quad * 8];
        #pragma unroll
        for (int i = 0; i < 4; i++) {
            short8 af = *(const short8*)&sA[i * 16 + l16][quad * 8];
            #pragma unroll
            for (int j = 0; j < CPW; j++)
                acc[i][j] = __builtin_amdgcn_mfma_f32_16x16x32_bf16(af, bf[j], acc[i][j], 0, 0, 0);
        }
    }
    if (SCORES) {
        __shared__ float sSD[64][CPW][2];
        for (int t = tid; t < 64 * CPW * 2; t += 256) ((float*)sSD)[t] = 0.0f;
        __syncthreads();
        const int hib = (wave * CPW * 16) >> 6;
        float avs[CPW], avd[CPW];
        #pragma unroll
        for (int j = 0; j < CPW; j++) {
            int c = col0 + wave * (CPW * 16) + j * 16 + l16;
            avs[j] = att_s[c];
            avd[j] = att_d[c];
        }
        #pragma unroll
        for (int i = 0; i < 4; i++) {
            float ps[4] = {0,0,0,0}, pd[4] = {0,0,0,0};
            #pragma unroll
            for (int j = 0; j < CPW; j++)
                #pragma unroll
                for (int r = 0; r < 4; r++) {
                    ps[r] += acc[i][j][r] * avs[j];
                    pd[r] += acc[i][j][r] * avd[j];
                }
            #pragma unroll
            for (int off = 1; off < 16; off <<= 1)
                #pragma unroll
                for (int r = 0; r < 4; r++) {
                    ps[r] += __shfl_xor(ps[r], off);
                    pd[r] += __shfl_xor(pd[r], off);
                }
            if (l16 == 0) {
                #pragma unroll
                for (int r = 0; r < 4; r++) {
                    atomicAdd(&sSD[i * 16 + quad * 4 + r][hib][0], ps[r]);
                    atomicAdd(&sSD[i * 16 + quad * 4 + r][hib][1], pd[r]);
                }
            }
        }
        __syncthreads();
        for (int t = tid; t < 64 * CPW; t += 256) {
            int row = t & 63, hb = t >> 6;
            int r = row0 + row;
            if (r < Nrows) {
                int hg = (col0 >> 6) + hb;
                a_s[(size_t)hg * Nrows + r] = sSD[row][hb][0] * LOG2E;   // head-major
                a_d[(size_t)hg * Nrows + r] = sSD[row][hb][1] * LOG2E;
            }
        }
    }
    #pragma unroll
    for (int i = 0; i < 4; i++) {
        #pragma unroll
        for (int j = 0; j < CPW; j++) {
            int col = col0 + wave * (CPW * 16) + j * 16 + l16;
            #pragma unroll
            for (int r = 0; r < 4; r++) {
                int row = row0 + i * 16 + quad * 4 + r;
                if (row < Nrows) {
                    if (SCORES) {
                        int head = col >> 6;
                        C16[(size_t)head * Nrows * 64 + (size_t)row * 64 + (col & 63)]
                            = f2b(acc[i][j][r]);
                    } else {
                        C16[(size_t)row * M + col] = f2b(acc[i][j][r]);
                    }
                }
            }
        }
    }
}

// ---------------- block-diagonal MFMA GEMM (conv1): out[:,h*64:+64] = ELU(agg_h @ W1_h + b) ----------------
__global__ __launch_bounds__(256) void gemm_bd64(const unsigned short* __restrict__ A16,
                                                 const unsigned short* __restrict__ Bt16,
                                                 const float* __restrict__ bias,
                                                 unsigned short* __restrict__ C16,
                                                 int Nrows) {
    __shared__ unsigned short sA[64][40];
    __shared__ unsigned short sB[64][40];
    const int tid = threadIdx.x;
    const int wave = tid >> 6;
    const int lane = tid & 63;
    const int quad = lane >> 4;
    const int l16 = lane & 15;
    const int h = blockIdx.y;
    const int row0 = blockIdx.x * 64;
    const int sr = tid >> 2;
    const int sk = (tid & 3) << 3;

    f32x4 acc[4];
    #pragma unroll
    for (int i = 0; i < 4; i++) acc[i] = (f32x4){0,0,0,0};

    #pragma unroll
    for (int kt = 0; kt < 64; kt += 32) {
        __syncthreads();
        {
            int r = row0 + sr;
            uint4 z = {0,0,0,0};
            *(uint4*)&sA[sr][sk] = (r < Nrows)
                ? *(const uint4*)&A16[(size_t)r * 256 + h * 64 + kt + sk] : z;
        }
        *(uint4*)&sB[sr][sk] = *(const uint4*)&Bt16[(size_t)(h * 64 + sr) * 64 + kt + sk];
        __syncthreads();
        short8 bf = *(const short8*)&sB[wave * 16 + l16][quad * 8];
        #pragma unroll
        for (int i = 0; i < 4; i++) {
            short8 af = *(const short8*)&sA[i * 16 + l16][quad * 8];
            acc[i] = __builtin_amdgcn_mfma_f32_16x16x32_bf16(af, bf, acc[i], 0, 0, 0);
        }
    }
    const int col = h * 64 + wave * 16 + l16;
    const float bb = bias[col];
    #pragma unroll
    for (int i = 0; i < 4; i++) {
        #pragma unroll
        for (int r = 0; r < 4; r++) {
            int row = row0 + i * 16 + quad * 4 + r;
            if (row < Nrows) {
                float v = acc[i][r] + bb;
                v = (v > 0.0f) ? v : expm1f(v);        // ELU
                C16[(size_t)row * 256 + col] = f2b(v);
            }
        }
    }
}

// ------------- CSR build -------------
__global__ void edge_hist_kernel(const int* __restrict__ ei, int* __restrict__ counts,
                                 int E, int Et) {
    int e = blockIdx.x * 256 + threadIdx.x;
    if (e >= Et) return;
    int d = (e < E) ? ei[E + e] : e - E;
    atomicAdd(&counts[d], 1);
}

__global__ __launch_bounds__(1024) void scan_blocks(int* __restrict__ counts,
                                                    int* __restrict__ blockSums, int N) {
    __shared__ int wsum[16];
    const int tid = threadIdx.x;
    const int lane = tid & 63;
    const int wave = tid >> 6;
    int i = blockIdx.x * 1024 + tid;
    int v = (i < N) ? counts[i] : 0;
    int s = v;
    #pragma unroll
    for (int off = 1; off < 64; off <<= 1) {
        int t = __shfl_up(s, off);
        if (lane >= off) s += t;
    }
    if (lane == 63) wsum[wave] = s;
    __syncthreads();
    if (wave == 0 && lane < 16) {
        int ws = wsum[lane];
        #pragma unroll
        for (int off = 1; off < 16; off <<= 1) {
            int t = __shfl_up(ws, off);
            if (lane >= off) ws += t;
        }
        wsum[lane] = ws;
    }
    __syncthreads();
    int waveOff = (wave > 0) ? wsum[wave - 1] : 0;
    int incl = s + waveOff;
    if (i < N) counts[i] = incl - v;
    if (tid == 1023) blockSums[blockIdx.x] = incl;
}

__global__ void scan_add2(const int* __restrict__ excl, const int* __restrict__ blockSums,
                          int nb, int* __restrict__ offsets, int* __restrict__ cursor,
                          int N, int Et) {
    __shared__ int sbs[64];
    if (threadIdx.x < 64) {
        int lane = threadIdx.x;
        int v = (lane < nb) ? blockSums[lane] : 0;
        int s = v;
        #pragma unroll
        for (int off = 1; off < 64; off <<= 1) {
            int t = __shfl_up(s, off);
            if (lane >= off) s += t;
        }
        sbs[lane] = s - v;                 // exclusive
    }
    __syncthreads();
    int i = blockIdx.x * 256 + threadIdx.x;
    if (i < N) {
        int o = excl[i] + sbs[i >> 10];
        offsets[i] = o;
        cursor[i] = o;
    }
    if (i == N) offsets[N] = Et;
}

__global__ void edge_sort_kernel(const int* __restrict__ ei, int* __restrict__ cursor,
                                 int* __restrict__ srcS, int E, int Et) {
    int e = blockIdx.x * 256 + threadIdx.x;
    if (e >= Et) return;
    int s, d;
    if (e < E) { s = ei[e]; d = ei[E + e]; } else { s = d = e - E; }
    int pos = atomicAdd(&cursor[d], 1);
    srcS[pos] = s;
}

// ------------- conv1 aggregate in INPUT space (64-dim, 4 per-head accumulators) -------------
__global__ __launch_bounds__(256) void gat_agg_in64(
        const int* __restrict__ offsets, const int* __restrict__ srcS,
        const float4* __restrict__ a_s4, const float4* __restrict__ a_d4,
        const unsigned short* __restrict__ h16,    // [N,64]
        unsigned short* __restrict__ out16,        // [N,256] = [head][64]
        int N) {
    __shared__ float wlds[4][64][4];
    __shared__ int slds[4][64];
    const int wid = threadIdx.x >> 6;
    const int n = blockIdx.x * 4 + wid;
    if (n >= N) return;
    const int lane = threadIdx.x & 63;
    const int half = lane >> 5;
    const int l32 = lane & 31;
    const int start = offsets[n], end = offsets[n + 1];
    const float4 ad = a_d4[n];
    float2 acc[4] = {{0,0},{0,0},{0,0},{0,0}};
    float4 den = {0,0,0,0};
    const int loff = l32 << 1;

    for (int e0 = start; e0 < end; e0 += 64) {
        const int cnt = min(64, end - e0);
        if (lane < cnt) {
            int sB = srcS[e0 + lane];
            slds[wid][lane] = sB;
            const float4 as = a_s4[sB];
            float x0 = as.x + ad.x; x0 = fmaxf(x0, NEG_SLOPE * x0);
            float x1 = as.y + ad.y; x1 = fmaxf(x1, NEG_SLOPE * x1);
            float x2 = as.z + ad.z; x2 = fmaxf(x2, NEG_SLOPE * x2);
            float x3 = as.w + ad.w; x3 = fmaxf(x3, NEG_SLOPE * x3);
            wlds[wid][lane][0] = exp2f(x0);
            wlds[wid][lane][1] = exp2f(x1);
            wlds[wid][lane][2] = exp2f(x2);
            wlds[wid][lane][3] = exp2f(x3);
        }
        int j = half;
        for (; j + 8 <= cnt + half; j += 8) {
            int ss[4]; float4 ww[4]; unsigned int gg[4];
            #pragma unroll
            for (int u = 0; u < 4; u++) {
                ss[u] = slds[wid][j + 2 * u];
                ww[u] = *(const float4*)&wlds[wid][j + 2 * u][0];
            }
            #pragma unroll
            for (int u = 0; u < 4; u++)
                gg[u] = *(const unsigned int*)&h16[((size_t)ss[u] << 6) + loff];
            #pragma unroll
            for (int u = 0; u < 4; u++) {
                const float vl = b2f_lo(gg[u]), vh = b2f_hi(gg[u]);
                acc[0].x += ww[u].x * vl; acc[0].y += ww[u].x * vh;
                acc[1].x += ww[u].y * vl; acc[1].y += ww[u].y * vh;
                acc[2].x += ww[u].z * vl; acc[2].y += ww[u].z * vh;
                acc[3].x += ww[u].w * vl; acc[3].y += ww[u].w * vh;
                den.x += ww[u].x; den.y += ww[u].y; den.z += ww[u].z; den.w += ww[u].w;
            }
        }
        for (; j < cnt; j += 2) {
            const int s = slds[wid][j];
            const float4 w = *(const float4*)&wlds[wid][j][0];
            const unsigned int g = *(const unsigned int*)&h16[((size_t)s << 6) + loff];
            const float vl = b2f_lo(g), vh = b2f_hi(g);
            acc[0].x += w.x * vl; acc[0].y += w.x * vh;
            acc[1].x += w.y * vl; acc[1].y += w.y * vh;
            acc[2].x += w.z * vl; acc[2].y += w.z * vh;
            acc[3].x += w.w * vl; acc[3].y += w.w * vh;
            den.x += w.x; den.y += w.y; den.z += w.z; den.w += w.w;
        }
    }
    #pragma unroll
    for (int h = 0; h < 4; h++) {
        acc[h].x += __shfl_xor(acc[h].x, 32);
        acc[h].y += __shfl_xor(acc[h].y, 32);
    }
    den.x += __shfl_xor(den.x, 32); den.y += __shfl_xor(den.y, 32);
    den.z += __shfl_xor(den.z, 32); den.w += __shfl_xor(den.w, 32);
    if (half == 0) {
        const float i0 = 1.0f / (den.x + 1e-16f);
        const float i1 = 1.0f / (den.y + 1e-16f);
        const float i2 = 1.0f / (den.z + 1e-16f);
        const float i3 = 1.0f / (den.w + 1e-16f);
        unsigned int o0 = (unsigned int)f2b(acc[0].x * i0) | ((unsigned int)f2b(acc[0].y * i0) << 16);
        unsigned int o1 = (unsigned int)f2b(acc[1].x * i1) | ((unsigned int)f2b(acc[1].y * i1) << 16);
        unsigned int o2 = (unsigned int)f2b(acc[2].x * i2) | ((unsigned int)f2b(acc[2].y * i2) << 16);
        unsigned int o3 = (unsigned int)f2b(acc[3].x * i3) | ((unsigned int)f2b(acc[3].y * i3) << 16);
        *(unsigned int*)&out16[(size_t)n * 256 + 0 * 64 + loff] = o0;
        *(unsigned int*)&out16[(size_t)n * 256 + 1 * 64 + loff] = o1;
        *(unsigned int*)&out16[(size_t)n * 256 + 2 * 64 + loff] = o2;
        *(unsigned int*)&out16[(size_t)n * 256 + 3 * 64 + loff] = o3;
    }
}

// ------------- conv2 aggregate, HEAD-MAJOR phases: blockIdx.y = head -------------
// wave = node; quad = edge slot (4 edges/issue); lane covers 4 channels (uint2).
// Gathers 128B rows from the head's 6.4MB table (L2-resident per phase).
__global__ __launch_bounds__(256) void gat_fused4h(
        const int* __restrict__ offsets, const int* __restrict__ srcS,
        const float* __restrict__ a_sH, const float* __restrict__ a_dH,   // [4][N]
        const unsigned short* __restrict__ hW16H,                         // [4][N][64]
        const float* __restrict__ bias,
        unsigned short* __restrict__ out16, int N) {
    __shared__ float wlds[4][64];
    __shared__ int slds[4][64];
    const int wid = threadIdx.x >> 6;
    const int n = blockIdx.x * 4 + wid;
    if (n >= N) return;
    const int head = blockIdx.y;
    const int lane = threadIdx.x & 63;
    const int quad = lane >> 4;
    const int l16 = lane & 15;
    const int start = offsets[n], end = offsets[n + 1];
    const float* __restrict__ a_s = a_sH + (size_t)head * N;
    const unsigned short* __restrict__ hW = hW16H + (size_t)head * N * 64;
    const float ad = a_dH[(size_t)head * N + n];
    const int coff = l16 << 2;                    // channel offset (4 ch/lane)
    float4 acc = {0, 0, 0, 0};
    float den = 0.0f;

    for (int e0 = start; e0 < end; e0 += 64) {
        const int cnt = min(64, end - e0);
        if (lane < cnt) {
            int sB = srcS[e0 + lane];
            slds[wid][lane] = sB;
            float ev = a_s[sB] + ad;
            ev = fmaxf(ev, NEG_SLOPE * ev);
            wlds[wid][lane] = exp2f(ev);
        }
        int j = quad;
        // x4 unroll: 16 edges per iteration, 4 independent loads in flight
        for (; j + 16 <= cnt + quad; j += 16) {
            int ss[4]; float ww[4]; uint2 hh[4];
            #pragma unroll
            for (int u = 0; u < 4; u++) {
                ss[u] = slds[wid][j + 4 * u];
                ww[u] = wlds[wid][j + 4 * u];
            }
            #pragma unroll
            for (int u = 0; u < 4; u++)
                hh[u] = *(const uint2*)&hW[((size_t)ss[u] << 6) + coff];
            #pragma unroll
            for (int u = 0; u < 4; u++) {
                acc.x += ww[u] * b2f_lo(hh[u].x); acc.y += ww[u] * b2f_hi(hh[u].x);
                acc.z += ww[u] * b2f_lo(hh[u].y); acc.w += ww[u] * b2f_hi(hh[u].y);
                den += ww[u];
            }
        }
        for (; j < cnt; j += 4) {
            const int s = slds[wid][j];
            const float w = wlds[wid][j];
            const uint2 hv = *(const uint2*)&hW[((size_t)s << 6) + coff];
            acc.x += w * b2f_lo(hv.x); acc.y += w * b2f_hi(hv.x);
            acc.z += w * b2f_lo(hv.y); acc.w += w * b2f_hi(hv.y);
            den += w;
        }
    }
    // reduce across quads (edge slots)
    #pragma unroll
    for (int off = 16; off < 64; off <<= 1) {
        acc.x += __shfl_xor(acc.x, off);
        acc.y += __shfl_xor(acc.y, off);
        acc.z += __shfl_xor(acc.z, off);
        acc.w += __shfl_xor(acc.w, off);
        den   += __shfl_xor(den, off);
    }
    if (quad == 0) {
        const float inv = 1.0f / (den + 1e-16f);
        const float4 bb = *(const float4*)&bias[head * 64 + coff];
        float v0 = acc.x * inv + bb.x; v0 = (v0 > 0.0f) ? v0 : expm1f(v0);
        float v1 = acc.y * inv + bb.y; v1 = (v1 > 0.0f) ? v1 : expm1f(v1);
        float v2 = acc.z * inv + bb.z; v2 = (v2 > 0.0f) ? v2 : expm1f(v2);
        float v3 = acc.w * inv + bb.w; v3 = (v3 > 0.0f) ? v3 : expm1f(v3);
        uint2 o;
        o.x = (unsigned int)f2b(v0) | ((unsigned int)f2b(v1) << 16);
        o.y = (unsigned int)f2b(v2) | ((unsigned int)f2b(v3) << 16);
        *(uint2*)&out16[(size_t)n * 256 + head * 64 + coff] = o;
    }
}

// ------------- H=1 fused (conv3): wave/node, LDS-batched weights, half-wave x4; fp32 out -------------
__global__ __launch_bounds__(256) void gat_fused1(
        const int* __restrict__ offsets, const int* __restrict__ srcS,
        const float* __restrict__ a_s, const float* __restrict__ a_d,
        const unsigned short* __restrict__ hW16, const float* __restrict__ bias,
        float* __restrict__ out, int N) {
    __shared__ float wlds[4][64];
    __shared__ int slds[4][64];
    const int wid = threadIdx.x >> 6;
    const int n = blockIdx.x * 4 + wid;
    if (n >= N) return;
    const int lane = threadIdx.x & 63;
    const int half = lane >> 5;
    const int l32 = lane & 31;
    const int start = offsets[n], end = offsets[n + 1];
    const float ad = a_d[n];
    float accx = 0.0f, accy = 0.0f, den = 0.0f;
    const int loff = l32 << 1;

    for (int e0 = start; e0 < end; e0 += 64) {
        const int cnt = min(64, end - e0);
        if (lane < cnt) {
            int sB = srcS[e0 + lane];
            slds[wid][lane] = sB;
            float ev = a_s[sB] + ad;
            ev = fmaxf(ev, NEG_SLOPE * ev);
            wlds[wid][lane] = exp2f(ev);
        }
        int j = half;
        for (; j + 8 <= cnt + half; j += 8) {
            const int s0 = slds[wid][j + 0];
            const int s1 = slds[wid][j + 2];
            const int s2 = slds[wid][j + 4];
            const int s3 = slds[wid][j + 6];
            const float w0 = wlds[wid][j + 0];
            const float w1 = wlds[wid][j + 2];
            const float w2 = wlds[wid][j + 4];
            const float w3 = wlds[wid][j + 6];
            const unsigned int h0 = *(const unsigned int*)&hW16[((size_t)s0 << 6) + loff];
            const unsigned int h1 = *(const unsigned int*)&hW16[((size_t)s1 << 6) + loff];
            const unsigned int h2 = *(const unsigned int*)&hW16[((size_t)s2 << 6) + loff];
            const unsigned int h3 = *(const unsigned int*)&hW16[((size_t)s3 << 6) + loff];
            accx += w0 * b2f_lo(h0); accy += w0 * b2f_hi(h0);
            accx += w1 * b2f_lo(h1); accy += w1 * b2f_hi(h1);
            accx += w2 * b2f_lo(h2); accy += w2 * b2f_hi(h2);
            accx += w3 * b2f_lo(h3); accy += w3 * b2f_hi(h3);
            den += (w0 + w1) + (w2 + w3);
        }
        for (; j < cnt; j += 2) {
            const int s = slds[wid][j];
            const float w = wlds[wid][j];
            const unsigned int hv = *(const unsigned int*)&hW16[((size_t)s << 6) + loff];
            accx += w * b2f_lo(hv);
            accy += w * b2f_hi(hv);
            den += w;
        }
    }
    accx += __shfl_xor(accx, 32);
    accy += __shfl_xor(accy, 32);
    den  += __shfl_xor(den, 32);
    if (half == 0) {
        const float inv = 1.0f / (den + 1e-16f);
        float2 o = {accx * inv + bias[loff], accy * inv + bias[loff + 1]};
        *(float2*)&out[(size_t)n * 64 + loff] = o;
    }
}

// ------------- per-graph mean pool (batch is sorted): chunked run-length accumulation -------------
__global__ void pool_kernel(const float* __restrict__ h, const int* __restrict__ batch,
                            float* __restrict__ pooled, float* __restrict__ cnt,
                            int N, int nWaves) {
    const int w = blockIdx.x * 4 + (threadIdx.x >> 6);
    const int lane = threadIdx.x & 63;
    const int chunk = (N + nWaves - 1) / nWaves;
    int start = w * chunk;
    int end = min(N, start + chunk);
    if (start >= end) return;
    int curg = batch[start];
    int runStart = start;
    float acc = 0.0f;
    for (int n = start; n < end; n++) {
        int g = batch[n];
        if (g != curg) {
            atomicAdd(&pooled[curg * 64 + lane], acc);
            if (lane == 0) atomicAdd(&cnt[curg], (float)(n - runStart));
            acc = 0.0f; curg = g; runStart = n;
        }
        acc += h[(size_t)n * 64 + lane];
    }
    atomicAdd(&pooled[curg * 64 + lane], acc);
    if (lane == 0) atomicAdd(&cnt[curg], (float)(end - runStart));
}

// ------------- decoder head: one block per graph -------------
__global__ __launch_bounds__(256) void final_kernel(
        const float* __restrict__ pooled, const float* __restrict__ cnt,
        const float* __restrict__ gf, const float* __restrict__ Wg,
        const float* __restrict__ bg, const float* __restrict__ Wd1,
        const float* __restrict__ bd1, const float* __restrict__ gamma,
        const float* __restrict__ beta, const float* __restrict__ Wd2,
        const float* __restrict__ bd2, float* __restrict__ out, int G) {
    const int g = blockIdx.x;
    const int tid = threadIdx.x;
    const int lane = tid & 63;
    const int wave = tid >> 6;
    __shared__ float spg[128];
    __shared__ float sz[64];
    __shared__ float wred[8];

    if (tid < 64) {
        spg[tid] = pooled[g * 64 + tid] / fmaxf(cnt[g], 1.0f);
    } else if (tid < 128) {
        int c = tid - 64;
        float v = bg[c];
        #pragma unroll
        for (int k = 0; k < 4; k++) v += gf[g * 4 + k] * Wg[k * 64 + c];
        spg[64 + c] = fmaxf(v, 0.0f);
    }
    __syncthreads();
    if (tid < 64) {
        float v = bd1[tid];
        #pragma unroll 8
        for (int k = 0; k < 128; k++) v += spg[k] * Wd1[k * 64 + tid];
        v = v * gamma[tid] + beta[tid];
        sz[tid] = fmaxf(v, 0.0f);
    }
    __syncthreads();
    float v = bd2[tid];
    #pragma unroll 8
    for (int k = 0; k < 64; k++) v += sz[k] * Wd2[k * 256 + tid];
    float m = v;
    #pragma unroll
    for (int off = 32; off > 0; off >>= 1) m = fmaxf(m, __shfl_xor(m, off));
    if (lane == 0) wred[wave] = m;
    __syncthreads();
    float M = fmaxf(fmaxf(wred[0], wred[1]), fmaxf(wred[2], wred[3]));
    float e = expf(v - M);
    float s = e;
    #pragma unroll
    for (int off = 32; off > 0; off >>= 1) s += __shfl_xor(s, off);
    if (lane == 0) wred[4 + wave] = s;
    __syncthreads();
    float S = (wred[4] + wred[5]) + (wred[6] + wred[7]);
    out[g * 256 + tid] = e / S;
}

extern "C" void kernel_launch(void* const* d_in, const int* in_sizes, int n_in,
                              void* d_out, int out_size, void* d_ws, size_t ws_size,
                              hipStream_t stream) {
    const float* x     = (const float*)d_in[0];
    const int*   ei    = (const int*)  d_in[1];
    const int*   batch = (const int*)  d_in[2];
    const float* gf    = (const float*)d_in[3];
    const float* W_enc = (const float*)d_in[4];
    const float* b_enc = (const float*)d_in[5];
    const float* W1  = (const float*)d_in[6];
    const float* as1 = (const float*)d_in[7];
    const float* ad1 = (const float*)d_in[8];
    const float* b1  = (const float*)d_in[9];
    const float* W2  = (const float*)d_in[10];
    const float* as2 = (const float*)d_in[11];
    const float* ad2 = (const float*)d_in[12];
    const float* b2  = (const float*)d_in[13];
    const float* W3  = (const float*)d_in[14];
    const float* as3 = (const float*)d_in[15];
    const float* ad3 = (const float*)d_in[16];
    const float* b3  = (const float*)d_in[17];
    const float* Wg  = (const float*)d_in[18];
    const float* bg  = (const float*)d_in[19];
    const float* Wd1 = (const float*)d_in[20];
    const float* bd1 = (const float*)d_in[21];
    const float* gm  = (const float*)d_in[22];
    const float* bt  = (const float*)d_in[23];
    const float* Wd2 = (const float*)d_in[24];
    const float* bd2 = (const float*)d_in[25];

    const int N  = in_sizes[2];
    const int E  = in_sizes[1] / 2;
    const int G  = in_sizes[3] / 4;
    const int Et = E + N;

    unsigned short* h16a = (unsigned short*)d_ws;                // [N,256] bf16 (or [4][N,64])
    unsigned short* h16b = h16a + (size_t)N * 256;               // [N,256] bf16
    unsigned short* h1_16 = h16b + (size_t)N * 256;              // [N,64] bf16
    unsigned short* Wt1  = h1_16 + (size_t)N * 64;               // [256,64]
    unsigned short* Wt2  = Wt1 + 256 * 64;                       // [256,256]
    unsigned short* Wt3  = Wt2 + 256 * 256;                      // [64,256]
    float* h3     = (float*)(Wt3 + 64 * 256);                    // [N,64] fp32
    float* a_s    = h3 + (size_t)N * 64;                         // [N,4] or [4][N]
    float* a_d    = a_s + (size_t)N * 4;                         // [N,4] or [4][N]
    float* u1s    = a_d + (size_t)N * 4;                         // [64,4]
    float* u1d    = u1s + 256;                                   // [64,4]
    float* pooled = u1d + 256;                                   // [G,64]
    float* cnt    = pooled + (size_t)G * 64;                     // [G]
    int*   offsets = (int*)(cnt + G);                            // [N+1]
    int*   srcS    = offsets + (N + 1);                          // [Et]
    int*   counts  = srcS + Et;                                  // [N]
    int*   cursor  = counts + N;                                 // [N]
    int*   blockSums = cursor + N;                               // [cdiv(N,1024)]

    dim3 blk(256);
    auto cdiv = [](int a, int b) { return (a + b - 1) / b; };
    const int eBlocks = cdiv(Et, 256);
    const int rowBlocks = cdiv(N, 64);
    const int nScanBlocks = cdiv(N, 1024);
    const int zc = cdiv(N, 256);

    // ---------------- prep (weights + zero-init) + CSR build ----------------
    prep_kernel<<<385 + zc + 5, blk, 0, stream>>>(W1, W2, W3, as1, ad1, Wt1, Wt2, Wt3,
                                                  u1s, u1d, counts, pooled, cnt, N, G, zc);
    edge_hist_kernel<<<eBlocks, blk, 0, stream>>>(ei, counts, E, Et);
    scan_blocks<<<nScanBlocks, 1024, 0, stream>>>(counts, blockSums, N);
    scan_add2<<<cdiv(N + 1, 256), blk, 0, stream>>>(counts, blockSums, nScanBlocks,
                                                    offsets, cursor, N, Et);
    edge_sort_kernel<<<eBlocks, blk, 0, stream>>>(ei, cursor, srcS, E, Et);

    // encoder: x -> h1 bf16, + fused conv1 scores ([N,4] layout for agg_in64)
    gemm_enc<<<dim3(rowBlocks, 1), blk, 0, stream>>>(x, W_enc, b_enc, h1_16,
                                                     u1s, u1d, a_s, a_d, N, 32, 64);

    // ---------------- conv1: aggregate in input space, then block-diag GEMM ----------------
    gat_agg_in64<<<cdiv(N, 4), blk, 0, stream>>>(offsets, srcS, (const float4*)a_s,
                                                 (const float4*)a_d, h1_16, h16a, N);
    gemm_bd64<<<dim3(rowBlocks, 4), blk, 0, stream>>>(h16a, Wt1, b1, h16b, N);

    // ---------------- conv2: GEMM (head-major out + head-major scores) -> per-head aggregate ----------------
    gemm_mfma<2, 1><<<dim3(rowBlocks, 2), blk, 0, stream>>>(h16b, Wt2, h16a,
                                                            as2, ad2, a_s, a_d, N, 256, 256, 4);
    gat_fused4h<<<dim3(cdiv(N, 4), 4), blk, 0, stream>>>(offsets, srcS, a_s, a_d,
                                                         h16a, b2, h16b, N);

    // ---------------- conv3: GEMM (+fused scores) -> aggregate -> pool ----------------
    gemm_mfma<1, 1><<<dim3(rowBlocks, 1), blk, 0, stream>>>(h16b, Wt3, h1_16,
                                                            as3, ad3, a_s, a_d, N, 256, 64, 1);
    gat_fused1<<<cdiv(N, 4), blk, 0, stream>>>(offsets, srcS, a_s, a_d, h1_16, b3, h3, N);
    pool_kernel<<<512, blk, 0, stream>>>(h3, batch, pooled, cnt, N, 512 * 4);

    // ---------------- decoder head ----------------
    final_kernel<<<G, blk, 0, stream>>>(pooled, cnt, gf, Wg, bg, Wd1, bd1, gm, bt, Wd2, bd2,
                                        (float*)d_out, G);
}

// Round 17
// 454.358 us; speedup vs baseline: 1.0973x; 1.0973x over previous
//
#include <hip/hip_runtime.h>
#include <math.h>

#define NEG_SLOPE 0.2f
#define LOG2E 1.4426950408889634f

typedef __attribute__((ext_vector_type(8))) short short8;   // 8 bf16 = 4 VGPRs
typedef __attribute__((ext_vector_type(4))) float f32x4;    // MFMA acc

__device__ inline float b2f(unsigned short u) {
    union { unsigned int i; float f; } x; x.i = ((unsigned int)u) << 16; return x.f;
}
__device__ inline float b2f_lo(unsigned int u) {
    union { unsigned int i; float f; } x; x.i = u << 16; return x.f;
}
__device__ inline float b2f_hi(unsigned int u) {
    union { unsigned int i; float f; } x; x.i = u & 0xFFFF0000u; return x.f;
}
__device__ inline unsigned short f2b(float f) {
    union { float f; unsigned int i; } u; u.f = f;
    unsigned int r = u.i + 0x7FFF + ((u.i >> 16) & 1);   // round-to-nearest-even
    return (unsigned short)(r >> 16);
}

// ---------------- combined prep: weight transposes, u1 vectors, and ALL zero-init ----------------
__global__ void prep_kernel(const float* __restrict__ W1, const float* __restrict__ W2,
                            const float* __restrict__ W3, const float* __restrict__ as1,
                            const float* __restrict__ ad1,
                            unsigned short* __restrict__ Wt1, unsigned short* __restrict__ Wt2,
                            unsigned short* __restrict__ Wt3,
                            float* __restrict__ u1s, float* __restrict__ u1d,
                            int* __restrict__ counts, float* __restrict__ pooled,
                            float* __restrict__ cnt, int N, int G, int zc) {
    const int b = blockIdx.x;
    const int t = threadIdx.x;
    if (b < 64) {
        int i = b * 256 + t;                    // K=64, M=256
        int k = i >> 8, m = i & 255;
        Wt1[(size_t)m * 64 + k] = f2b(W1[i]);
    } else if (b < 320) {
        int i = (b - 64) * 256 + t;             // K=256, M=256
        int k = i >> 8, m = i & 255;
        Wt2[(size_t)m * 256 + k] = f2b(W2[i]);
    } else if (b < 384) {
        int i = (b - 320) * 256 + t;            // K=256, M=64
        int k = i >> 6, m = i & 63;
        Wt3[(size_t)m * 256 + k] = f2b(W3[i]);
    } else if (b == 384) {
        int k = t >> 2, h = t & 3;
        float s = 0.0f, d = 0.0f;
        for (int c = 0; c < 64; c++) {
            float w = W1[k * 256 + h * 64 + c];
            s += w * as1[h * 64 + c];
            d += w * ad1[h * 64 + c];
        }
        u1s[k * 4 + h] = s;
        u1d[k * 4 + h] = d;
    } else if (b < 385 + zc) {
        int i = (b - 385) * 256 + t;
        if (i < N) counts[i] = 0;
    } else {
        int i = (b - 385 - zc) * 256 + t;
        if (i < G * 64) pooled[i] = 0.0f;
        if (i < G) cnt[i] = 0.0f;
    }
}

// ---------------- encoder GEMM: fp32 compute, bf16 out + bias; fused conv1 scores ----------------
__global__ __launch_bounds__(256) void gemm_enc(const float* __restrict__ A,
                                                const float* __restrict__ B,
                                                const float* __restrict__ bias,
                                                unsigned short* __restrict__ C16,
                                                const float* __restrict__ u1s,
                                                const float* __restrict__ u1d,
                                                float* __restrict__ a_s,   // [N,4]
                                                float* __restrict__ a_d,
                                                int Nrows, int K, int M) {
    __shared__ float sA[16][64];
    __shared__ float sB[16][64];
    const int tx = threadIdx.x & 15;
    const int ty = threadIdx.x >> 4;
    const int row0 = blockIdx.x * 64;
    const int lr = threadIdx.x >> 2;
    const int lk = (threadIdx.x & 3) << 2;
    const int br = threadIdx.x >> 4;
    const int bc = (threadIdx.x & 15) << 2;

    const int aRow = row0 + lr;
    const bool aValid = aRow < Nrows;
    const float* Aptr = A + (size_t)aRow * K + lk;
    const float* Bptr = B + (size_t)br * M + bc;

    float acc[4][4] = {{0,0,0,0},{0,0,0,0},{0,0,0,0},{0,0,0,0}};
    float4 a = aValid ? *(const float4*)Aptr : float4{0,0,0,0};
    float4 b = *(const float4*)Bptr;

    for (int kt = 0; kt < K; kt += 16) {
        __syncthreads();
        sA[lk+0][lr] = a.x; sA[lk+1][lr] = a.y; sA[lk+2][lr] = a.z; sA[lk+3][lr] = a.w;
        *(float4*)&sB[br][bc] = b;
        __syncthreads();
        if (kt + 16 < K) {
            a = aValid ? *(const float4*)(Aptr + kt + 16) : float4{0,0,0,0};
            b = *(const float4*)(Bptr + (size_t)(kt + 16) * M);
        }
        #pragma unroll
        for (int k = 0; k < 16; k++) {
            const float4 av = *(const float4*)&sA[k][ty << 2];
            const float4 bv = *(const float4*)&sB[k][tx << 2];
            acc[0][0] += av.x*bv.x; acc[0][1] += av.x*bv.y; acc[0][2] += av.x*bv.z; acc[0][3] += av.x*bv.w;
            acc[1][0] += av.y*bv.x; acc[1][1] += av.y*bv.y; acc[1][2] += av.y*bv.z; acc[1][3] += av.y*bv.w;
            acc[2][0] += av.z*bv.x; acc[2][1] += av.z*bv.y; acc[2][2] += av.z*bv.z; acc[2][3] += av.z*bv.w;
            acc[3][0] += av.w*bv.x; acc[3][1] += av.w*bv.y; acc[3][2] += av.w*bv.z; acc[3][3] += av.w*bv.w;
        }
    }
    float4 bb = *(const float4*)&bias[tx << 2];
    #pragma unroll
    for (int i = 0; i < 4; i++) {
        acc[i][0] += bb.x; acc[i][1] += bb.y; acc[i][2] += bb.z; acc[i][3] += bb.w;
    }
    float4 us[4], ud[4];
    #pragma unroll
    for (int j = 0; j < 4; j++) {
        us[j] = *(const float4*)&u1s[((tx << 2) + j) * 4];
        ud[j] = *(const float4*)&u1d[((tx << 2) + j) * 4];
    }
    #pragma unroll
    for (int i = 0; i < 4; i++) {
        float4 ps = {0,0,0,0}, pd = {0,0,0,0};
        #pragma unroll
        for (int j = 0; j < 4; j++) {
            ps.x += acc[i][j] * us[j].x; ps.y += acc[i][j] * us[j].y;
            ps.z += acc[i][j] * us[j].z; ps.w += acc[i][j] * us[j].w;
            pd.x += acc[i][j] * ud[j].x; pd.y += acc[i][j] * ud[j].y;
            pd.z += acc[i][j] * ud[j].z; pd.w += acc[i][j] * ud[j].w;
        }
        #pragma unroll
        for (int off = 1; off < 16; off <<= 1) {
            ps.x += __shfl_xor(ps.x, off); ps.y += __shfl_xor(ps.y, off);
            ps.z += __shfl_xor(ps.z, off); ps.w += __shfl_xor(ps.w, off);
            pd.x += __shfl_xor(pd.x, off); pd.y += __shfl_xor(pd.y, off);
            pd.z += __shfl_xor(pd.z, off); pd.w += __shfl_xor(pd.w, off);
        }
        int r = row0 + (ty << 2) + i;
        if (tx == 0 && r < Nrows) {
            float4 o1 = {ps.x * LOG2E, ps.y * LOG2E, ps.z * LOG2E, ps.w * LOG2E};
            float4 o2 = {pd.x * LOG2E, pd.y * LOG2E, pd.z * LOG2E, pd.w * LOG2E};
            *(float4*)&a_s[r * 4] = o1;
            *(float4*)&a_d[r * 4] = o2;
        }
    }
    #pragma unroll
    for (int i = 0; i < 4; i++) {
        int r = row0 + (ty << 2) + i;
        if (r < Nrows) {
            ushort4 o = {f2b(acc[i][0]), f2b(acc[i][1]), f2b(acc[i][2]), f2b(acc[i][3])};
            *(ushort4*)&C16[(size_t)r * M + (tx << 2)] = o;
        }
    }
}

// ---------------- MFMA GEMM: C16[N,M] = A16[N,K] @ Wt16^T; optional fused scores ----------------
template<int CPW, int SCORES>
__global__ __launch_bounds__(256) void gemm_mfma(const unsigned short* __restrict__ A16,
                                                 const unsigned short* __restrict__ Bt16,
                                                 unsigned short* __restrict__ C16,
                                                 const float* __restrict__ att_s,
                                                 const float* __restrict__ att_d,
                                                 float* __restrict__ a_s,
                                                 float* __restrict__ a_d,
                                                 int Nrows, int K, int M, int H) {
    constexpr int BN = CPW * 64;
    __shared__ unsigned short sA[64][40];
    __shared__ unsigned short sB[BN][40];
    const int tid = threadIdx.x;
    const int wave = tid >> 6;
    const int lane = tid & 63;
    const int quad = lane >> 4;
    const int l16 = lane & 15;
    const int row0 = blockIdx.x * 64;
    const int col0 = blockIdx.y * BN;
    const int sr = tid >> 2;
    const int sk = (tid & 3) << 3;

    f32x4 acc[4][CPW];
    #pragma unroll
    for (int i = 0; i < 4; i++)
        #pragma unroll
        for (int j = 0; j < CPW; j++) acc[i][j] = (f32x4){0,0,0,0};

    for (int kt = 0; kt < K; kt += 32) {
        __syncthreads();
        {
            int r = row0 + sr;
            uint4 z = {0,0,0,0};
            *(uint4*)&sA[sr][sk] = (r < Nrows) ? *(const uint4*)&A16[(size_t)r * K + kt + sk] : z;
        }
        #pragma unroll
        for (int i = 0; i < CPW; i++) {
            int c = col0 + sr + i * 64;
            *(uint4*)&sB[sr + i * 64][sk] = *(const uint4*)&Bt16[(size_t)c * K + kt + sk];
        }
        __syncthreads();
        short8 bf[CPW];
        #pragma unroll
        for (int j = 0; j < CPW; j++)
            bf[j] = *(const short8*)&sB[wave * (CPW * 16) + j * 16 + l16][quad * 8];
        #pragma unroll
        for (int i = 0; i < 4; i++) {
            short8 af = *(const short8*)&sA[i * 16 + l16][quad * 8];
            #pragma unroll
            for (int j = 0; j < CPW; j++)
                acc[i][j] = __builtin_amdgcn_mfma_f32_16x16x32_bf16(af, bf[j], acc[i][j], 0, 0, 0);
        }
    }
    if (SCORES) {
        __shared__ float sSD[64][CPW][2];
        for (int t = tid; t < 64 * CPW * 2; t += 256) ((float*)sSD)[t] = 0.0f;
        __syncthreads();
        const int hib = (wave * CPW * 16) >> 6;
        float avs[CPW], avd[CPW];
        #pragma unroll
        for (int j = 0; j < CPW; j++) {
            int c = col0 + wave * (CPW * 16) + j * 16 + l16;
            avs[j] = att_s[c];
            avd[j] = att_d[c];
        }
        #pragma unroll
        for (int i = 0; i < 4; i++) {
            float ps[4] = {0,0,0,0}, pd[4] = {0,0,0,0};
            #pragma unroll
            for (int j = 0; j < CPW; j++)
                #pragma unroll
                for (int r = 0; r < 4; r++) {
                    ps[r] += acc[i][j][r] * avs[j];
                    pd[r] += acc[i][j][r] * avd[j];
                }
            #pragma unroll
            for (int off = 1; off < 16; off <<= 1)
                #pragma unroll
                for (int r = 0; r < 4; r++) {
                    ps[r] += __shfl_xor(ps[r], off);
                    pd[r] += __shfl_xor(pd[r], off);
                }
            if (l16 == 0) {
                #pragma unroll
                for (int r = 0; r < 4; r++) {
                    atomicAdd(&sSD[i * 16 + quad * 4 + r][hib][0], ps[r]);
                    atomicAdd(&sSD[i * 16 + quad * 4 + r][hib][1], pd[r]);
                }
            }
        }
        __syncthreads();
        for (int t = tid; t < 64 * CPW; t += 256) {
            int row = t & 63, hb = t >> 6;
            int r = row0 + row;
            if (r < Nrows) {
                int hg = (col0 >> 6) + hb;
                a_s[r * H + hg] = sSD[row][hb][0] * LOG2E;
                a_d[r * H + hg] = sSD[row][hb][1] * LOG2E;
            }
        }
    }
    #pragma unroll
    for (int i = 0; i < 4; i++) {
        #pragma unroll
        for (int j = 0; j < CPW; j++) {
            int col = col0 + wave * (CPW * 16) + j * 16 + l16;
            #pragma unroll
            for (int r = 0; r < 4; r++) {
                int row = row0 + i * 16 + quad * 4 + r;
                if (row < Nrows) C16[(size_t)row * M + col] = f2b(acc[i][j][r]);
            }
        }
    }
}

// ---------------- block-diagonal MFMA GEMM (conv1): out[:,h*64:+64] = ELU(agg_h @ W1_h + b) ----------------
__global__ __launch_bounds__(256) void gemm_bd64(const unsigned short* __restrict__ A16,
                                                 const unsigned short* __restrict__ Bt16,
                                                 const float* __restrict__ bias,
                                                 unsigned short* __restrict__ C16,
                                                 int Nrows) {
    __shared__ unsigned short sA[64][40];
    __shared__ unsigned short sB[64][40];
    const int tid = threadIdx.x;
    const int wave = tid >> 6;
    const int lane = tid & 63;
    const int quad = lane >> 4;
    const int l16 = lane & 15;
    const int h = blockIdx.y;
    const int row0 = blockIdx.x * 64;
    const int sr = tid >> 2;
    const int sk = (tid & 3) << 3;

    f32x4 acc[4];
    #pragma unroll
    for (int i = 0; i < 4; i++) acc[i] = (f32x4){0,0,0,0};

    #pragma unroll
    for (int kt = 0; kt < 64; kt += 32) {
        __syncthreads();
        {
            int r = row0 + sr;
            uint4 z = {0,0,0,0};
            *(uint4*)&sA[sr][sk] = (r < Nrows)
                ? *(const uint4*)&A16[(size_t)r * 256 + h * 64 + kt + sk] : z;
        }
        *(uint4*)&sB[sr][sk] = *(const uint4*)&Bt16[(size_t)(h * 64 + sr) * 64 + kt + sk];
        __syncthreads();
        short8 bf = *(const short8*)&sB[wave * 16 + l16][quad * 8];
        #pragma unroll
        for (int i = 0; i < 4; i++) {
            short8 af = *(const short8*)&sA[i * 16 + l16][quad * 8];
            acc[i] = __builtin_amdgcn_mfma_f32_16x16x32_bf16(af, bf, acc[i], 0, 0, 0);
        }
    }
    const int col = h * 64 + wave * 16 + l16;
    const float bb = bias[col];
    #pragma unroll
    for (int i = 0; i < 4; i++) {
        #pragma unroll
        for (int r = 0; r < 4; r++) {
            int row = row0 + i * 16 + quad * 4 + r;
            if (row < Nrows) {
                float v = acc[i][r] + bb;
                v = (v > 0.0f) ? v : expm1f(v);        // ELU
                C16[(size_t)row * 256 + col] = f2b(v);
            }
        }
    }
}

// ------------- CSR build -------------
__global__ void edge_hist_kernel(const int* __restrict__ ei, int* __restrict__ counts,
                                 int E, int Et) {
    int e = blockIdx.x * 256 + threadIdx.x;
    if (e >= Et) return;
    int d = (e < E) ? ei[E + e] : e - E;
    atomicAdd(&counts[d], 1);
}

__global__ __launch_bounds__(1024) void scan_blocks(int* __restrict__ counts,
                                                    int* __restrict__ blockSums, int N) {
    __shared__ int wsum[16];
    const int tid = threadIdx.x;
    const int lane = tid & 63;
    const int wave = tid >> 6;
    int i = blockIdx.x * 1024 + tid;
    int v = (i < N) ? counts[i] : 0;
    int s = v;
    #pragma unroll
    for (int off = 1; off < 64; off <<= 1) {
        int t = __shfl_up(s, off);
        if (lane >= off) s += t;
    }
    if (lane == 63) wsum[wave] = s;
    __syncthreads();
    if (wave == 0 && lane < 16) {
        int ws = wsum[lane];
        #pragma unroll
        for (int off = 1; off < 16; off <<= 1) {
            int t = __shfl_up(ws, off);
            if (lane >= off) ws += t;
        }
        wsum[lane] = ws;
    }
    __syncthreads();
    int waveOff = (wave > 0) ? wsum[wave - 1] : 0;
    int incl = s + waveOff;
    if (i < N) counts[i] = incl - v;
    if (tid == 1023) blockSums[blockIdx.x] = incl;
}

__global__ void scan_add2(const int* __restrict__ excl, const int* __restrict__ blockSums,
                          int nb, int* __restrict__ offsets, int* __restrict__ cursor,
                          int N, int Et) {
    __shared__ int sbs[64];
    if (threadIdx.x < 64) {
        int lane = threadIdx.x;
        int v = (lane < nb) ? blockSums[lane] : 0;
        int s = v;
        #pragma unroll
        for (int off = 1; off < 64; off <<= 1) {
            int t = __shfl_up(s, off);
            if (lane >= off) s += t;
        }
        sbs[lane] = s - v;                 // exclusive
    }
    __syncthreads();
    int i = blockIdx.x * 256 + threadIdx.x;
    if (i < N) {
        int o = excl[i] + sbs[i >> 10];
        offsets[i] = o;
        cursor[i] = o;
    }
    if (i == N) offsets[N] = Et;
}

__global__ void edge_sort_kernel(const int* __restrict__ ei, int* __restrict__ cursor,
                                 int* __restrict__ srcS, int E, int Et) {
    int e = blockIdx.x * 256 + threadIdx.x;
    if (e >= Et) return;
    int s, d;
    if (e < E) { s = ei[e]; d = ei[E + e]; } else { s = d = e - E; }
    int pos = atomicAdd(&cursor[d], 1);
    srcS[pos] = s;
}

// ------------- conv1 aggregate in INPUT space (64-dim, 4 per-head accumulators) -------------
__global__ __launch_bounds__(256) void gat_agg_in64(
        const int* __restrict__ offsets, const int* __restrict__ srcS,
        const float4* __restrict__ a_s4, const float4* __restrict__ a_d4,
        const unsigned short* __restrict__ h16,    // [N,64]
        unsigned short* __restrict__ out16,        // [N,256] = [head][64]
        int N) {
    __shared__ float wlds[4][64][4];
    __shared__ int slds[4][64];
    const int wid = threadIdx.x >> 6;
    const int n = blockIdx.x * 4 + wid;
    if (n >= N) return;
    const int lane = threadIdx.x & 63;
    const int half = lane >> 5;
    const int l32 = lane & 31;
    const int start = offsets[n], end = offsets[n + 1];
    const float4 ad = a_d4[n];
    float2 acc[4] = {{0,0},{0,0},{0,0},{0,0}};
    float4 den = {0,0,0,0};
    const int loff = l32 << 1;

    for (int e0 = start; e0 < end; e0 += 64) {
        const int cnt = min(64, end - e0);
        if (lane < cnt) {
            int sB = srcS[e0 + lane];
            slds[wid][lane] = sB;
            const float4 as = a_s4[sB];
            float x0 = as.x + ad.x; x0 = fmaxf(x0, NEG_SLOPE * x0);
            float x1 = as.y + ad.y; x1 = fmaxf(x1, NEG_SLOPE * x1);
            float x2 = as.z + ad.z; x2 = fmaxf(x2, NEG_SLOPE * x2);
            float x3 = as.w + ad.w; x3 = fmaxf(x3, NEG_SLOPE * x3);
            wlds[wid][lane][0] = exp2f(x0);
            wlds[wid][lane][1] = exp2f(x1);
            wlds[wid][lane][2] = exp2f(x2);
            wlds[wid][lane][3] = exp2f(x3);
        }
        int j = half;
        for (; j + 8 <= cnt + half; j += 8) {
            int ss[4]; float4 ww[4]; unsigned int gg[4];
            #pragma unroll
            for (int u = 0; u < 4; u++) {
                ss[u] = slds[wid][j + 2 * u];
                ww[u] = *(const float4*)&wlds[wid][j + 2 * u][0];
            }
            #pragma unroll
            for (int u = 0; u < 4; u++)
                gg[u] = *(const unsigned int*)&h16[((size_t)ss[u] << 6) + loff];
            #pragma unroll
            for (int u = 0; u < 4; u++) {
                const float vl = b2f_lo(gg[u]), vh = b2f_hi(gg[u]);
                acc[0].x += ww[u].x * vl; acc[0].y += ww[u].x * vh;
                acc[1].x += ww[u].y * vl; acc[1].y += ww[u].y * vh;
                acc[2].x += ww[u].z * vl; acc[2].y += ww[u].z * vh;
                acc[3].x += ww[u].w * vl; acc[3].y += ww[u].w * vh;
                den.x += ww[u].x; den.y += ww[u].y; den.z += ww[u].z; den.w += ww[u].w;
            }
        }
        for (; j < cnt; j += 2) {
            const int s = slds[wid][j];
            const float4 w = *(const float4*)&wlds[wid][j][0];
            const unsigned int g = *(const unsigned int*)&h16[((size_t)s << 6) + loff];
            const float vl = b2f_lo(g), vh = b2f_hi(g);
            acc[0].x += w.x * vl; acc[0].y += w.x * vh;
            acc[1].x += w.y * vl; acc[1].y += w.y * vh;
            acc[2].x += w.z * vl; acc[2].y += w.z * vh;
            acc[3].x += w.w * vl; acc[3].y += w.w * vh;
            den.x += w.x; den.y += w.y; den.z += w.z; den.w += w.w;
        }
    }
    #pragma unroll
    for (int h = 0; h < 4; h++) {
        acc[h].x += __shfl_xor(acc[h].x, 32);
        acc[h].y += __shfl_xor(acc[h].y, 32);
    }
    den.x += __shfl_xor(den.x, 32); den.y += __shfl_xor(den.y, 32);
    den.z += __shfl_xor(den.z, 32); den.w += __shfl_xor(den.w, 32);
    if (half == 0) {
        const float i0 = 1.0f / (den.x + 1e-16f);
        const float i1 = 1.0f / (den.y + 1e-16f);
        const float i2 = 1.0f / (den.z + 1e-16f);
        const float i3 = 1.0f / (den.w + 1e-16f);
        unsigned int o0 = (unsigned int)f2b(acc[0].x * i0) | ((unsigned int)f2b(acc[0].y * i0) << 16);
        unsigned int o1 = (unsigned int)f2b(acc[1].x * i1) | ((unsigned int)f2b(acc[1].y * i1) << 16);
        unsigned int o2 = (unsigned int)f2b(acc[2].x * i2) | ((unsigned int)f2b(acc[2].y * i2) << 16);
        unsigned int o3 = (unsigned int)f2b(acc[3].x * i3) | ((unsigned int)f2b(acc[3].y * i3) << 16);
        *(unsigned int*)&out16[(size_t)n * 256 + 0 * 64 + loff] = o0;
        *(unsigned int*)&out16[(size_t)n * 256 + 1 * 64 + loff] = o1;
        *(unsigned int*)&out16[(size_t)n * 256 + 2 * 64 + loff] = o2;
        *(unsigned int*)&out16[(size_t)n * 256 + 3 * 64 + loff] = o3;
    }
}

// ------------- conv2 aggregate (output space, 256-dim), x4 unrolled gather, +bias+ELU -------------
__global__ __launch_bounds__(256) void gat_fused4(
        const int* __restrict__ offsets, const int* __restrict__ srcS,
        const float4* __restrict__ a_s4, const float4* __restrict__ a_d4,
        const unsigned short* __restrict__ hW16, const float* __restrict__ bias,
        unsigned short* __restrict__ out16, int N) {
    __shared__ float wlds[4][64][4];
    __shared__ int slds[4][64];
    const int wid = threadIdx.x >> 6;
    const int n = blockIdx.x * 4 + wid;
    if (n >= N) return;
    const int lane = threadIdx.x & 63;
    const int quad = lane >> 4;
    const int start = offsets[n], end = offsets[n + 1];
    const float4 ad = a_d4[n];
    float4 acc = {0, 0, 0, 0};
    float den = 0.0f;
    const int loff = lane << 2;

    for (int e0 = start; e0 < end; e0 += 64) {
        const int cnt = min(64, end - e0);
        if (lane < cnt) {
            int sB = srcS[e0 + lane];
            slds[wid][lane] = sB;
            const float4 as = a_s4[sB];
            float x0 = as.x + ad.x; x0 = fmaxf(x0, NEG_SLOPE * x0);
            float x1 = as.y + ad.y; x1 = fmaxf(x1, NEG_SLOPE * x1);
            float x2 = as.z + ad.z; x2 = fmaxf(x2, NEG_SLOPE * x2);
            float x3 = as.w + ad.w; x3 = fmaxf(x3, NEG_SLOPE * x3);
            wlds[wid][lane][0] = exp2f(x0);
            wlds[wid][lane][1] = exp2f(x1);
            wlds[wid][lane][2] = exp2f(x2);
            wlds[wid][lane][3] = exp2f(x3);
        }
        int j = 0;
        for (; j + 4 <= cnt; j += 4) {
            const int s0 = __builtin_amdgcn_readfirstlane(slds[wid][j + 0]);
            const int s1 = __builtin_amdgcn_readfirstlane(slds[wid][j + 1]);
            const int s2 = __builtin_amdgcn_readfirstlane(slds[wid][j + 2]);
            const int s3 = __builtin_amdgcn_readfirstlane(slds[wid][j + 3]);
            const float w0 = wlds[wid][j + 0][quad];
            const float w1 = wlds[wid][j + 1][quad];
            const float w2 = wlds[wid][j + 2][quad];
            const float w3 = wlds[wid][j + 3][quad];
            const uint2 h0 = *(const uint2*)&hW16[((size_t)s0 << 8) + loff];
            const uint2 h1 = *(const uint2*)&hW16[((size_t)s1 << 8) + loff];
            const uint2 h2 = *(const uint2*)&hW16[((size_t)s2 << 8) + loff];
            const uint2 h3 = *(const uint2*)&hW16[((size_t)s3 << 8) + loff];
            acc.x += w0 * b2f_lo(h0.x); acc.y += w0 * b2f_hi(h0.x);
            acc.z += w0 * b2f_lo(h0.y); acc.w += w0 * b2f_hi(h0.y);
            acc.x += w1 * b2f_lo(h1.x); acc.y += w1 * b2f_hi(h1.x);
            acc.z += w1 * b2f_lo(h1.y); acc.w += w1 * b2f_hi(h1.y);
            acc.x += w2 * b2f_lo(h2.x); acc.y += w2 * b2f_hi(h2.x);
            acc.z += w2 * b2f_lo(h2.y); acc.w += w2 * b2f_hi(h2.y);
            acc.x += w3 * b2f_lo(h3.x); acc.y += w3 * b2f_hi(h3.x);
            acc.z += w3 * b2f_lo(h3.y); acc.w += w3 * b2f_hi(h3.y);
            den += (w0 + w1) + (w2 + w3);
        }
        for (; j < cnt; j++) {
            const int s = __builtin_amdgcn_readfirstlane(slds[wid][j]);
            const float w = wlds[wid][j][quad];
            const uint2 hv = *(const uint2*)&hW16[((size_t)s << 8) + loff];
            acc.x += w * b2f_lo(hv.x); acc.y += w * b2f_hi(hv.x);
            acc.z += w * b2f_lo(hv.y); acc.w += w * b2f_hi(hv.y);
            den += w;
        }
    }

    const float inv = 1.0f / (den + 1e-16f);
    const float4 bb = *(const float4*)&bias[loff];
    float v0 = acc.x * inv + bb.x; v0 = (v0 > 0.0f) ? v0 : expm1f(v0);
    float v1 = acc.y * inv + bb.y; v1 = (v1 > 0.0f) ? v1 : expm1f(v1);
    float v2 = acc.z * inv + bb.z; v2 = (v2 > 0.0f) ? v2 : expm1f(v2);
    float v3 = acc.w * inv + bb.w; v3 = (v3 > 0.0f) ? v3 : expm1f(v3);
    uint2 o;
    o.x = (unsigned int)f2b(v0) | ((unsigned int)f2b(v1) << 16);
    o.y = (unsigned int)f2b(v2) | ((unsigned int)f2b(v3) << 16);
    *(uint2*)&out16[(size_t)n * 256 + loff] = o;
}

// ------------- H=1 fused (conv3): wave/node, LDS-batched weights, half-wave x4; fp32 out -------------
__global__ __launch_bounds__(256) void gat_fused1(
        const int* __restrict__ offsets, const int* __restrict__ srcS,
        const float* __restrict__ a_s, const float* __restrict__ a_d,
        const unsigned short* __restrict__ hW16, const float* __restrict__ bias,
        float* __restrict__ out, int N) {
    __shared__ float wlds[4][64];
    __shared__ int slds[4][64];
    const int wid = threadIdx.x >> 6;
    const int n = blockIdx.x * 4 + wid;
    if (n >= N) return;
    const int lane = threadIdx.x & 63;
    const int half = lane >> 5;
    const int l32 = lane & 31;
    const int start = offsets[n], end = offsets[n + 1];
    const float ad = a_d[n];
    float accx = 0.0f, accy = 0.0f, den = 0.0f;
    const int loff = l32 << 1;

    for (int e0 = start; e0 < end; e0 += 64) {
        const int cnt = min(64, end - e0);
        if (lane < cnt) {
            int sB = srcS[e0 + lane];
            slds[wid][lane] = sB;
            float ev = a_s[sB] + ad;
            ev = fmaxf(ev, NEG_SLOPE * ev);
            wlds[wid][lane] = exp2f(ev);
        }
        int j = half;
        for (; j + 8 <= cnt + half; j += 8) {
            const int s0 = slds[wid][j + 0];
            const int s1 = slds[wid][j + 2];
            const int s2 = slds[wid][j + 4];
            const int s3 = slds[wid][j + 6];
            const float w0 = wlds[wid][j + 0];
            const float w1 = wlds[wid][j + 2];
            const float w2 = wlds[wid][j + 4];
            const float w3 = wlds[wid][j + 6];
            const unsigned int h0 = *(const unsigned int*)&hW16[((size_t)s0 << 6) + loff];
            const unsigned int h1 = *(const unsigned int*)&hW16[((size_t)s1 << 6) + loff];
            const unsigned int h2 = *(const unsigned int*)&hW16[((size_t)s2 << 6) + loff];
            const unsigned int h3 = *(const unsigned int*)&hW16[((size_t)s3 << 6) + loff];
            accx += w0 * b2f_lo(h0); accy += w0 * b2f_hi(h0);
            accx += w1 * b2f_lo(h1); accy += w1 * b2f_hi(h1);
            accx += w2 * b2f_lo(h2); accy += w2 * b2f_hi(h2);
            accx += w3 * b2f_lo(h3); accy += w3 * b2f_hi(h3);
            den += (w0 + w1) + (w2 + w3);
        }
        for (; j < cnt; j += 2) {
            const int s = slds[wid][j];
            const float w = wlds[wid][j];
            const unsigned int hv = *(const unsigned int*)&hW16[((size_t)s << 6) + loff];
            accx += w * b2f_lo(hv);
            accy += w * b2f_hi(hv);
            den += w;
        }
    }
    accx += __shfl_xor(accx, 32);
    accy += __shfl_xor(accy, 32);
    den  += __shfl_xor(den, 32);
    if (half == 0) {
        const float inv = 1.0f / (den + 1e-16f);
        float2 o = {accx * inv + bias[loff], accy * inv + bias[loff + 1]};
        *(float2*)&out[(size_t)n * 64 + loff] = o;
    }
}

// ------------- per-graph mean pool (batch is sorted): chunked run-length accumulation -------------
__global__ void pool_kernel(const float* __restrict__ h, const int* __restrict__ batch,
                            float* __restrict__ pooled, float* __restrict__ cnt,
                            int N, int nWaves) {
    const int w = blockIdx.x * 4 + (threadIdx.x >> 6);
    const int lane = threadIdx.x & 63;
    const int chunk = (N + nWaves - 1) / nWaves;
    int start = w * chunk;
    int end = min(N, start + chunk);
    if (start >= end) return;
    int curg = batch[start];
    int runStart = start;
    float acc = 0.0f;
    for (int n = start; n < end; n++) {
        int g = batch[n];
        if (g != curg) {
            atomicAdd(&pooled[curg * 64 + lane], acc);
            if (lane == 0) atomicAdd(&cnt[curg], (float)(n - runStart));
            acc = 0.0f; curg = g; runStart = n;
        }
        acc += h[(size_t)n * 64 + lane];
    }
    atomicAdd(&pooled[curg * 64 + lane], acc);
    if (lane == 0) atomicAdd(&cnt[curg], (float)(end - runStart));
}

// ------------- decoder head: one block per graph -------------
__global__ __launch_bounds__(256) void final_kernel(
        const float* __restrict__ pooled, const float* __restrict__ cnt,
        const float* __restrict__ gf, const float* __restrict__ Wg,
        const float* __restrict__ bg, const float* __restrict__ Wd1,
        const float* __restrict__ bd1, const float* __restrict__ gamma,
        const float* __restrict__ beta, const float* __restrict__ Wd2,
        const float* __restrict__ bd2, float* __restrict__ out, int G) {
    const int g = blockIdx.x;
    const int tid = threadIdx.x;
    const int lane = tid & 63;
    const int wave = tid >> 6;
    __shared__ float spg[128];
    __shared__ float sz[64];
    __shared__ float wred[8];

    if (tid < 64) {
        spg[tid] = pooled[g * 64 + tid] / fmaxf(cnt[g], 1.0f);
    } else if (tid < 128) {
        int c = tid - 64;
        float v = bg[c];
        #pragma unroll
        for (int k = 0; k < 4; k++) v += gf[g * 4 + k] * Wg[k * 64 + c];
        spg[64 + c] = fmaxf(v, 0.0f);
    }
    __syncthreads();
    if (tid < 64) {
        float v = bd1[tid];
        #pragma unroll 8
        for (int k = 0; k < 128; k++) v += spg[k] * Wd1[k * 64 + tid];
        v = v * gamma[tid] + beta[tid];
        sz[tid] = fmaxf(v, 0.0f);
    }
    __syncthreads();
    float v = bd2[tid];
    #pragma unroll 8
    for (int k = 0; k < 64; k++) v += sz[k] * Wd2[k * 256 + tid];
    float m = v;
    #pragma unroll
    for (int off = 32; off > 0; off >>= 1) m = fmaxf(m, __shfl_xor(m, off));
    if (lane == 0) wred[wave] = m;
    __syncthreads();
    float M = fmaxf(fmaxf(wred[0], wred[1]), fmaxf(wred[2], wred[3]));
    float e = expf(v - M);
    float s = e;
    #pragma unroll
    for (int off = 32; off > 0; off >>= 1) s += __shfl_xor(s, off);
    if (lane == 0) wred[4 + wave] = s;
    __syncthreads();
    float S = (wred[4] + wred[5]) + (wred[6] + wred[7]);
    out[g * 256 + tid] = e / S;
}

extern "C" void kernel_launch(void* const* d_in, const int* in_sizes, int n_in,
                              void* d_out, int out_size, void* d_ws, size_t ws_size,
                              hipStream_t stream) {
    const float* x     = (const float*)d_in[0];
    const int*   ei    = (const int*)  d_in[1];
    const int*   batch = (const int*)  d_in[2];
    const float* gf    = (const float*)d_in[3];
    const float* W_enc = (const float*)d_in[4];
    const float* b_enc = (const float*)d_in[5];
    const float* W1  = (const float*)d_in[6];
    const float* as1 = (const float*)d_in[7];
    const float* ad1 = (const float*)d_in[8];
    const float* b1  = (const float*)d_in[9];
    const float* W2  = (const float*)d_in[10];
    const float* as2 = (const float*)d_in[11];
    const float* ad2 = (const float*)d_in[12];
    const float* b2  = (const float*)d_in[13];
    const float* W3  = (const float*)d_in[14];
    const float* as3 = (const float*)d_in[15];
    const float* ad3 = (const float*)d_in[16];
    const float* b3  = (const float*)d_in[17];
    const float* Wg  = (const float*)d_in[18];
    const float* bg  = (const float*)d_in[19];
    const float* Wd1 = (const float*)d_in[20];
    const float* bd1 = (const float*)d_in[21];
    const float* gm  = (const float*)d_in[22];
    const float* bt  = (const float*)d_in[23];
    const float* Wd2 = (const float*)d_in[24];
    const float* bd2 = (const float*)d_in[25];

    const int N  = in_sizes[2];
    const int E  = in_sizes[1] / 2;
    const int G  = in_sizes[3] / 4;
    const int Et = E + N;

    unsigned short* h16a = (unsigned short*)d_ws;                // [N,256] bf16
    unsigned short* h16b = h16a + (size_t)N * 256;               // [N,256] bf16
    unsigned short* h1_16 = h16b + (size_t)N * 256;              // [N,64] bf16
    unsigned short* Wt1  = h1_16 + (size_t)N * 64;               // [256,64]
    unsigned short* Wt2  = Wt1 + 256 * 64;                       // [256,256]
    unsigned short* Wt3  = Wt2 + 256 * 256;                      // [64,256]
    float* h3     = (float*)(Wt3 + 64 * 256);                    // [N,64] fp32
    float* a_s    = h3 + (size_t)N * 64;                         // [N,4]
    float* a_d    = a_s + (size_t)N * 4;                         // [N,4]
    float* u1s    = a_d + (size_t)N * 4;                         // [64,4]
    float* u1d    = u1s + 256;                                   // [64,4]
    float* pooled = u1d + 256;                                   // [G,64]
    float* cnt    = pooled + (size_t)G * 64;                     // [G]
    int*   offsets = (int*)(cnt + G);                            // [N+1]
    int*   srcS    = offsets + (N + 1);                          // [Et]
    int*   counts  = srcS + Et;                                  // [N]
    int*   cursor  = counts + N;                                 // [N]
    int*   blockSums = cursor + N;                               // [cdiv(N,1024)]

    dim3 blk(256);
    auto cdiv = [](int a, int b) { return (a + b - 1) / b; };
    const int eBlocks = cdiv(Et, 256);
    const int rowBlocks = cdiv(N, 64);
    const int nScanBlocks = cdiv(N, 1024);
    const int zc = cdiv(N, 256);

    // ---------------- prep (weights + zero-init) + CSR build ----------------
    prep_kernel<<<385 + zc + 5, blk, 0, stream>>>(W1, W2, W3, as1, ad1, Wt1, Wt2, Wt3,
                                                  u1s, u1d, counts, pooled, cnt, N, G, zc);
    edge_hist_kernel<<<eBlocks, blk, 0, stream>>>(ei, counts, E, Et);
    scan_blocks<<<nScanBlocks, 1024, 0, stream>>>(counts, blockSums, N);
    scan_add2<<<cdiv(N + 1, 256), blk, 0, stream>>>(counts, blockSums, nScanBlocks,
                                                    offsets, cursor, N, Et);
    edge_sort_kernel<<<eBlocks, blk, 0, stream>>>(ei, cursor, srcS, E, Et);

    // encoder: x -> h1 bf16, + fused conv1 scores
    gemm_enc<<<dim3(rowBlocks, 1), blk, 0, stream>>>(x, W_enc, b_enc, h1_16,
                                                     u1s, u1d, a_s, a_d, N, 32, 64);

    // ---------------- conv1: aggregate in input space, then block-diag GEMM ----------------
    gat_agg_in64<<<cdiv(N, 4), blk, 0, stream>>>(offsets, srcS, (const float4*)a_s,
                                                 (const float4*)a_d, h1_16, h16a, N);
    gemm_bd64<<<dim3(rowBlocks, 4), blk, 0, stream>>>(h16a, Wt1, b1, h16b, N);

    // ---------------- conv2: GEMM (+fused scores) -> aggregate ----------------
    gemm_mfma<2, 1><<<dim3(rowBlocks, 2), blk, 0, stream>>>(h16b, Wt2, h16a,
                                                            as2, ad2, a_s, a_d, N, 256, 256, 4);
    gat_fused4<<<cdiv(N, 4), blk, 0, stream>>>(offsets, srcS, (const float4*)a_s,
                                               (const float4*)a_d, h16a, b2, h16b, N);

    // ---------------- conv3: GEMM (+fused scores) -> aggregate -> pool ----------------
    gemm_mfma<1, 1><<<dim3(rowBlocks, 1), blk, 0, stream>>>(h16b, Wt3, h1_16,
                                                            as3, ad3, a_s, a_d, N, 256, 64, 1);
    gat_fused1<<<cdiv(N, 4), blk, 0, stream>>>(offsets, srcS, a_s, a_d, h1_16, b3, h3, N);
    pool_kernel<<<512, blk, 0, stream>>>(h3, batch, pooled, cnt, N, 512 * 4);

    // ---------------- decoder head ----------------
    final_kernel<<<G, blk, 0, stream>>>(pooled, cnt, gf, Wg, bg, Wd1, bd1, gm, bt, Wd2, bd2,
                                        (float*)d_out, G);
}